// Round 7
// baseline (253.964 us; speedup 1.0000x reference)
//
#include <hip/hip_runtime.h>

typedef unsigned short u16;
typedef unsigned int   u32;

using short8 = __attribute__((ext_vector_type(8))) short;
using f32x4  = __attribute__((ext_vector_type(4))) float;
using half8  = __attribute__((ext_vector_type(8))) _Float16;

// SCALE * log2(e) folded into q at the QKV epilogue
#define QSCALE 0.18033688011112042f

__device__ __forceinline__ u16 f2bf(float f) {
  u32 u = __float_as_uint(f);
  return (u16)((u + 0x8000u) >> 16);
}
__device__ __forceinline__ u16 f2h(float f) {
  _Float16 h = (_Float16)f;
  return __builtin_bit_cast(u16, h);
}

// async global->LDS DMA, 16B per lane; lds dest = wave-uniform base + lane*16
__device__ __forceinline__ void gld16(const u16* g, u16* l) {
  __builtin_amdgcn_global_load_lds(
      (const __attribute__((address_space(1))) unsigned int*)g,
      (__attribute__((address_space(3))) unsigned int*)l, 16, 0, 0);
}

// ---------------- x fp32 -> bf16, 4 elems/thread ----------------
__global__ __launch_bounds__(256) void cvt_x(const float* __restrict__ in,
                                             u16* __restrict__ out) {
  int idx = blockIdx.x * 256 + threadIdx.x;
  float4 v = reinterpret_cast<const float4*>(in)[idx];
  ushort4 o;
  o.x = f2bf(v.x); o.y = f2bf(v.y); o.z = f2bf(v.z); o.w = f2bf(v.w);
  reinterpret_cast<ushort4*>(out)[idx] = o;
}

// ---------------- fp32 [R][C] -> bf16 [C][R] (B^T layout for GEMM) ----------------
__global__ __launch_bounds__(256) void transpose_w(const float* __restrict__ in,
                                                   u16* __restrict__ out,
                                                   int R, int C) {
  __shared__ u32 s[32][33];
  int c0 = blockIdx.x * 32, r0 = blockIdx.y * 32;
  int j = threadIdx.x & 31, i0 = threadIdx.x >> 5;
#pragma unroll
  for (int p = 0; p < 4; ++p) {
    int i = i0 + p * 8;
    s[i][j] = f2bf(in[(size_t)(r0 + i) * C + c0 + j]);
  }
  __syncthreads();
#pragma unroll
  for (int p = 0; p < 4; ++p) {
    int jj = i0 + p * 8;
    out[(size_t)(c0 + jj) * R + r0 + j] = (u16)s[j][jj];
  }
}

// ---------------- bf16 MFMA GEMM: C[M,N] = A[M,K] @ Bt[N,K]^T + bias ----------------
// m97 structure, block tile (32*MT) x 128, BK=32, global_load_lds width-16
// staging with XOR-swizzled LDS. EPI==0 (MT=4): scatter qkv (q pre-scaled by
// SCALE*log2e; v written fp16 transposed [bh][d][t]). EPI==1 (MT=2): fp32 C.
template <int EPI, int MT>
__global__ __launch_bounds__(256, 3) void gemm_bt(
    const u16* __restrict__ A, const u16* __restrict__ Bt,
    const float* __restrict__ bias, float* __restrict__ c_out,
    u16* __restrict__ q_out, u16* __restrict__ k_out, u16* __restrict__ vt_out,
    int M, int N, int K) {
  __shared__ __align__(16) u16 As[32 * MT * 32];
  __shared__ __align__(16) u16 Bs[128 * 32];
  const int tid = threadIdx.x;
  const int lane = tid & 63;
  const int wv = tid >> 6;
  const int l16 = lane & 15, quad = lane >> 4;
  const int wm = wv & 1, wn = wv >> 1;
  const int bx = blockIdx.x, by = blockIdx.y;

  const u16* Ab = A + (size_t)by * (32 * MT) * K;
  const u16* Bb = Bt + (size_t)bx * 128 * K;

  const f32x4 fzero = {0.0f, 0.0f, 0.0f, 0.0f};
  f32x4 acc[MT][4];
#pragma unroll
  for (int i = 0; i < MT; ++i)
#pragma unroll
    for (int j = 0; j < 4; ++j) acc[i][j] = fzero;

  for (int k0 = 0; k0 < K; k0 += 32) {
    __syncthreads();
#pragma unroll
    for (int p = 0; p < MT / 2; ++p) {
      int id = p * 256 + tid;
      int row = id >> 2, blk = id & 3;
      int gc = k0 + ((blk ^ (row & 3)) << 3);
      gld16(Ab + (size_t)row * K + gc, &As[id << 3]);
    }
#pragma unroll
    for (int p = 0; p < 2; ++p) {
      int id = p * 256 + tid;
      int row = id >> 2, blk = id & 3;
      int gc = k0 + ((blk ^ (row & 3)) << 3);
      gld16(Bb + (size_t)row * K + gc, &Bs[id << 3]);
    }
    __syncthreads();
    short8 af[MT], bfr[4];
#pragma unroll
    for (int mi = 0; mi < MT; ++mi) {
      int row = wm * (MT * 16) + mi * 16 + l16;
      af[mi] = *reinterpret_cast<const short8*>(&As[row * 32 + ((quad ^ (row & 3)) << 3)]);
    }
#pragma unroll
    for (int ni = 0; ni < 4; ++ni) {
      int row = wn * 64 + ni * 16 + l16;
      bfr[ni] = *reinterpret_cast<const short8*>(&Bs[row * 32 + ((quad ^ (row & 3)) << 3)]);
    }
#pragma unroll
    for (int mi = 0; mi < MT; ++mi)
#pragma unroll
      for (int ni = 0; ni < 4; ++ni)
        acc[mi][ni] = __builtin_amdgcn_mfma_f32_16x16x32_bf16(af[mi], bfr[ni], acc[mi][ni], 0, 0, 0);
  }

  // epilogue: C row = quad*4+r (A dim), col = l16 (B dim)
#pragma unroll
  for (int mi = 0; mi < MT; ++mi)
#pragma unroll
    for (int ni = 0; ni < 4; ++ni) {
      int col = bx * 128 + wn * 64 + ni * 16 + l16;
      float bv = bias[col];
      int row0 = by * (32 * MT) + wm * (MT * 16) + mi * 16 + quad * 4;
      if (EPI == 1) {
#pragma unroll
        for (int r = 0; r < 4; ++r)
          c_out[(size_t)(row0 + r) * N + col] = acc[mi][ni][r] + bv;
      } else {
        int which = col >> 10, rem = col & 1023;
        int h = rem >> 6, d = rem & 63;
        int b = row0 >> 11, sq0 = row0 & 2047;
        int bh = (b << 4) + h;
        if (which == 2) {
          // V fp16 transposed [bh][d][t]; 4 consecutive t -> one 8B store
          ushort4 pk;
          pk.x = f2h(acc[mi][ni][0] + bv);
          pk.y = f2h(acc[mi][ni][1] + bv);
          pk.z = f2h(acc[mi][ni][2] + bv);
          pk.w = f2h(acc[mi][ni][3] + bv);
          *reinterpret_cast<ushort4*>(&vt_out[(size_t)bh * 131072 + d * 2048 + sq0]) = pk;
        } else {
          size_t base = (size_t)(bh * 2048 + sq0) * 64 + d;
#pragma unroll
          for (int r = 0; r < 4; ++r) {
            float val = acc[mi][ni][r] + bv;
            if (which == 0) q_out[base + r * 64] = f2bf(val * QSCALE);
            else            k_out[base + r * 64] = f2bf(val);
          }
        }
      }
    }
}

// ---------------- flash attention (all-x32 MFMA, zero-barrier loop) ----------
// 64 Q rows/block, 4 waves t-split, 32 t/wave/iter (block iter = 128 t, 16
// iters). QK feeds permuted K-rows t = 8*(l16>>2)+(l16&3) (+4 for tile B) so
// the two S^T C-tiles give lane t = quad*8+j for q=l16 — exactly the
// mfma_f32_16x16x32_f16 A-frag: P is a register half8, PV runs at x32 rate.
// K frags register-double-buffered, V JIT from plain [bh][d][t] fp16, Q frags
// register-resident. No LDS / no barriers in the loop; 16 KB LDS only for the
// final cross-wave O/l reduction. Grid (bh, q): blocks of one bh share an XCD.
__global__ __launch_bounds__(256, 3) void attn(
    const u16* __restrict__ q_buf, const u16* __restrict__ k_buf,
    const u16* __restrict__ vt_buf, u16* __restrict__ o_buf) {
  __shared__ __align__(16) float red[4][4][256];  // 16 KB
  __shared__ float lred[4][16];

  const int tid = threadIdx.x;
  const int lane = tid & 63, w = tid >> 6;
  const int l16 = lane & 15, quad = lane >> 4;
  const int bh = blockIdx.x, q0 = blockIdx.y * 64;

  const u16* qg = q_buf + (size_t)bh * 131072 + q0 * 64;
  // permuted K row for QK tile A: t = w*32 + 8*(l16>>2) + (l16&3)
  const u16* kp = k_buf + (size_t)bh * 131072 +
                  (w * 32 + ((l16 >> 2) << 3) + (l16 & 3)) * 64 + quad * 8;
  // V [d][t]: lane d=l16 (tile nd adds 16), t = w*32 + quad*8
  const u16* vp = vt_buf + (size_t)bh * 131072 + l16 * 2048 + w * 32 + quad * 8;

  // Q B-frags (loop-invariant): n=q=l16, k = kk*32 + quad*8 + j
  short8 qb[4][2];
#pragma unroll
  for (int qi = 0; qi < 4; ++qi)
#pragma unroll
    for (int kk = 0; kk < 2; ++kk)
      qb[qi][kk] = *reinterpret_cast<const short8*>(
          qg + (qi * 16 + l16) * 64 + kk * 32 + quad * 8);

  const f32x4 fzero = {0.0f, 0.0f, 0.0f, 0.0f};
  f32x4 o_acc[4][4];
  float l_acc[4] = {0.f, 0.f, 0.f, 0.f};
#pragma unroll
  for (int qi = 0; qi < 4; ++qi)
#pragma unroll
    for (int nd = 0; nd < 4; ++nd) o_acc[qi][nd] = fzero;

  // K frag double-buffer: [0]=tileA kk0, [1]=tileA kk1, [2]=tileB kk0, [3]=tileB kk1
  short8 ka[2][4];
  ka[0][0] = *reinterpret_cast<const short8*>(kp);
  ka[0][1] = *reinterpret_cast<const short8*>(kp + 32);
  ka[0][2] = *reinterpret_cast<const short8*>(kp + 256);   // +4 rows
  ka[0][3] = *reinterpret_cast<const short8*>(kp + 288);

#pragma unroll 2
  for (int i = 0; i < 16; ++i) {
    const int buf = i & 1, nb = buf ^ 1;

    // V JIT for this iter (consumed after QK+exp2 -> latency slack)
    half8 vf[4];
#pragma unroll
    for (int nd = 0; nd < 4; ++nd)
      vf[nd] = *reinterpret_cast<const half8*>(vp + nd * 16 * 2048);

    // K prefetch for next iter
    if (i + 1 < 16) {
      const u16* kn = kp + 128 * 64;
      ka[nb][0] = *reinterpret_cast<const short8*>(kn);
      ka[nb][1] = *reinterpret_cast<const short8*>(kn + 32);
      ka[nb][2] = *reinterpret_cast<const short8*>(kn + 256);
      ka[nb][3] = *reinterpret_cast<const short8*>(kn + 288);
      kp = kn;
    }

#pragma unroll
    for (int qi = 0; qi < 4; ++qi) {
      // S^T tiles A/B: m = permuted t, n = q
      f32x4 sA = __builtin_amdgcn_mfma_f32_16x16x32_bf16(ka[buf][0], qb[qi][0], fzero, 0, 0, 0);
      sA = __builtin_amdgcn_mfma_f32_16x16x32_bf16(ka[buf][1], qb[qi][1], sA, 0, 0, 0);
      f32x4 sB = __builtin_amdgcn_mfma_f32_16x16x32_bf16(ka[buf][2], qb[qi][0], fzero, 0, 0, 0);
      sB = __builtin_amdgcn_mfma_f32_16x16x32_bf16(ka[buf][3], qb[qi][1], sB, 0, 0, 0);
      // P = exp2(S^T): lane q=l16 holds t = quad*8 + {0..3 from A, 4..7 from B}
      float p0 = __builtin_amdgcn_exp2f(sA[0]);
      float p1 = __builtin_amdgcn_exp2f(sA[1]);
      float p2 = __builtin_amdgcn_exp2f(sA[2]);
      float p3 = __builtin_amdgcn_exp2f(sA[3]);
      float p4 = __builtin_amdgcn_exp2f(sB[0]);
      float p5 = __builtin_amdgcn_exp2f(sB[1]);
      float p6 = __builtin_amdgcn_exp2f(sB[2]);
      float p7 = __builtin_amdgcn_exp2f(sB[3]);
      l_acc[qi] += ((p0 + p1) + (p2 + p3)) + ((p4 + p5) + (p6 + p7));
      half8 pa;
      pa[0] = (_Float16)p0; pa[1] = (_Float16)p1;
      pa[2] = (_Float16)p2; pa[3] = (_Float16)p3;
      pa[4] = (_Float16)p4; pa[5] = (_Float16)p5;
      pa[6] = (_Float16)p6; pa[7] = (_Float16)p7;
      // O += P.V at x32 rate
#pragma unroll
      for (int nd = 0; nd < 4; ++nd)
        o_acc[qi][nd] = __builtin_amdgcn_mfma_f32_16x16x32_f16(pa, vf[nd], o_acc[qi][nd], 0, 0, 0);
    }
    vp += 128;
  }

  // l: reduce across quads -> every lane holds this wave's l for q=l16
#pragma unroll
  for (int qi = 0; qi < 4; ++qi) {
    l_acc[qi] += __shfl_xor(l_acc[qi], 16, 64);
    l_acc[qi] += __shfl_xor(l_acc[qi], 32, 64);
  }

  // cross-wave O/l reduction per qi-phase through LDS
  const int b = bh >> 4, h = bh & 15;
#pragma unroll
  for (int qi = 0; qi < 4; ++qi) {
#pragma unroll
    for (int nd = 0; nd < 4; ++nd)
      *reinterpret_cast<f32x4*>(&red[w][nd][lane * 4]) = o_acc[qi][nd];
    if (lane < 16) lred[w][lane] = l_acc[qi];
    __syncthreads();
    // wave w reduces & writes d-columns [w*16, w*16+16)
    f32x4 os = fzero, lv = fzero;
#pragma unroll
    for (int wp = 0; wp < 4; ++wp) {
      os += *reinterpret_cast<const f32x4*>(&red[wp][w][lane * 4]);
      lv += *reinterpret_cast<const f32x4*>(&lred[wp][quad * 4]);
    }
#pragma unroll
    for (int r = 0; r < 4; ++r) {
      int sq = q0 + qi * 16 + quad * 4 + r;
      o_buf[(size_t)(b * 2048 + sq) * 1024 + h * 64 + w * 16 + l16] =
          f2bf(os[r] / lv[r]);
    }
    __syncthreads();
  }
}

extern "C" void kernel_launch(void* const* d_in, const int* in_sizes, int n_in,
                              void* d_out, int out_size, void* d_ws, size_t ws_size,
                              hipStream_t stream) {
  (void)in_sizes; (void)n_in; (void)out_size; (void)ws_size;
  const float* x     = (const float*)d_in[0];
  const float* W_qkv = (const float*)d_in[1];
  const float* b_qkv = (const float*)d_in[2];
  const float* W_out = (const float*)d_in[3];
  const float* b_out = (const float*)d_in[4];
  float* out = (float*)d_out;

  // workspace layout (48 MB total)
  char* ws = (char*)d_ws;
  u16* x_bf   = (u16*)(ws);              //  8 MB  [4096][1024] bf16
  u16* wqkv_t = (u16*)(ws + 8388608);    //  6 MB  [3072][1024] bf16
  u16* wout_t = (u16*)(ws + 14680064);   //  2 MB  [1024][1024] bf16
  u16* q_buf  = (u16*)(ws + 16777216);   //  8 MB  [32][2048][64] bf16
  u16* k_buf  = (u16*)(ws + 25165824);   //  8 MB  [32][2048][64] bf16
  u16* vt_buf = (u16*)(ws + 33554432);   //  8 MB  [32][64][2048] fp16 V^T
  u16* o_bf   = (u16*)(ws + 41943040);   //  8 MB  [4096][1024] bf16

  cvt_x<<<4096, 256, 0, stream>>>(x, x_bf);
  transpose_w<<<dim3(96, 32), 256, 0, stream>>>(W_qkv, wqkv_t, 1024, 3072);
  transpose_w<<<dim3(32, 32), 256, 0, stream>>>(W_out, wout_t, 1024, 1024);
  gemm_bt<0, 4><<<dim3(24, 32), 256, 0, stream>>>(x_bf, wqkv_t, b_qkv, nullptr,
                                                  q_buf, k_buf, vt_buf, 4096, 3072, 1024);
  attn<<<dim3(32, 32), 256, 0, stream>>>(q_buf, k_buf, vt_buf, o_bf);
  gemm_bt<1, 2><<<dim3(8, 64), 256, 0, stream>>>(o_bf, wout_t, b_out, out,
                                                 nullptr, nullptr, nullptr, 4096, 1024, 1024);
}

// Round 8
// 224.994 us; speedup vs baseline: 1.1288x; 1.1288x over previous
//
#include <hip/hip_runtime.h>

typedef unsigned short u16;
typedef unsigned int   u32;

using short8 = __attribute__((ext_vector_type(8))) short;
using f32x4  = __attribute__((ext_vector_type(4))) float;
using half8  = __attribute__((ext_vector_type(8))) _Float16;

// SCALE * log2(e) folded into q at the QKV epilogue
#define QSCALE 0.18033688011112042f

__device__ __forceinline__ u16 f2bf(float f) {
  u32 u = __float_as_uint(f);
  return (u16)((u + 0x8000u) >> 16);
}
__device__ __forceinline__ u16 f2h(float f) {
  _Float16 h = (_Float16)f;
  return __builtin_bit_cast(u16, h);
}

// async global->LDS DMA, 16B per lane; lds dest = wave-uniform base + lane*16
__device__ __forceinline__ void gld16(const u16* g, u16* l) {
  __builtin_amdgcn_global_load_lds(
      (const __attribute__((address_space(1))) unsigned int*)g,
      (__attribute__((address_space(3))) unsigned int*)l, 16, 0, 0);
}

// ---------------- x fp32 -> bf16, 4 elems/thread ----------------
__global__ __launch_bounds__(256) void cvt_x(const float* __restrict__ in,
                                             u16* __restrict__ out) {
  int idx = blockIdx.x * 256 + threadIdx.x;
  float4 v = reinterpret_cast<const float4*>(in)[idx];
  ushort4 o;
  o.x = f2bf(v.x); o.y = f2bf(v.y); o.z = f2bf(v.z); o.w = f2bf(v.w);
  reinterpret_cast<ushort4*>(out)[idx] = o;
}

// ---------------- fp32 [R][C] -> bf16 [C][R] (B^T layout for GEMM) ----------------
__global__ __launch_bounds__(256) void transpose_w(const float* __restrict__ in,
                                                   u16* __restrict__ out,
                                                   int R, int C) {
  __shared__ u32 s[32][33];
  int c0 = blockIdx.x * 32, r0 = blockIdx.y * 32;
  int j = threadIdx.x & 31, i0 = threadIdx.x >> 5;
#pragma unroll
  for (int p = 0; p < 4; ++p) {
    int i = i0 + p * 8;
    s[i][j] = f2bf(in[(size_t)(r0 + i) * C + c0 + j]);
  }
  __syncthreads();
#pragma unroll
  for (int p = 0; p < 4; ++p) {
    int jj = i0 + p * 8;
    out[(size_t)(c0 + jj) * R + r0 + j] = (u16)s[j][jj];
  }
}

// ---------------- bf16 MFMA GEMM: C[M,N] = A[M,K] @ Bt[N,K]^T + bias ----------------
// m97 structure, block tile (32*MT) x 128, BK=32, global_load_lds width-16
// staging with XOR-swizzled LDS. EPI==0 (MT=4): scatter qkv (q pre-scaled by
// SCALE*log2e; v written fp16 transposed [bh][d][t]). EPI==1 (MT=2): fp32 C.
template <int EPI, int MT>
__global__ __launch_bounds__(256, 3) void gemm_bt(
    const u16* __restrict__ A, const u16* __restrict__ Bt,
    const float* __restrict__ bias, float* __restrict__ c_out,
    u16* __restrict__ q_out, u16* __restrict__ k_out, u16* __restrict__ vt_out,
    int M, int N, int K) {
  __shared__ __align__(16) u16 As[32 * MT * 32];
  __shared__ __align__(16) u16 Bs[128 * 32];
  const int tid = threadIdx.x;
  const int lane = tid & 63;
  const int wv = tid >> 6;
  const int l16 = lane & 15, quad = lane >> 4;
  const int wm = wv & 1, wn = wv >> 1;
  const int bx = blockIdx.x, by = blockIdx.y;

  const u16* Ab = A + (size_t)by * (32 * MT) * K;
  const u16* Bb = Bt + (size_t)bx * 128 * K;

  const f32x4 fzero = {0.0f, 0.0f, 0.0f, 0.0f};
  f32x4 acc[MT][4];
#pragma unroll
  for (int i = 0; i < MT; ++i)
#pragma unroll
    for (int j = 0; j < 4; ++j) acc[i][j] = fzero;

  for (int k0 = 0; k0 < K; k0 += 32) {
    __syncthreads();
#pragma unroll
    for (int p = 0; p < MT / 2; ++p) {
      int id = p * 256 + tid;
      int row = id >> 2, blk = id & 3;
      int gc = k0 + ((blk ^ (row & 3)) << 3);
      gld16(Ab + (size_t)row * K + gc, &As[id << 3]);
    }
#pragma unroll
    for (int p = 0; p < 2; ++p) {
      int id = p * 256 + tid;
      int row = id >> 2, blk = id & 3;
      int gc = k0 + ((blk ^ (row & 3)) << 3);
      gld16(Bb + (size_t)row * K + gc, &Bs[id << 3]);
    }
    __syncthreads();
    short8 af[MT], bfr[4];
#pragma unroll
    for (int mi = 0; mi < MT; ++mi) {
      int row = wm * (MT * 16) + mi * 16 + l16;
      af[mi] = *reinterpret_cast<const short8*>(&As[row * 32 + ((quad ^ (row & 3)) << 3)]);
    }
#pragma unroll
    for (int ni = 0; ni < 4; ++ni) {
      int row = wn * 64 + ni * 16 + l16;
      bfr[ni] = *reinterpret_cast<const short8*>(&Bs[row * 32 + ((quad ^ (row & 3)) << 3)]);
    }
#pragma unroll
    for (int mi = 0; mi < MT; ++mi)
#pragma unroll
      for (int ni = 0; ni < 4; ++ni)
        acc[mi][ni] = __builtin_amdgcn_mfma_f32_16x16x32_bf16(af[mi], bfr[ni], acc[mi][ni], 0, 0, 0);
  }

  // epilogue: C row = quad*4+r (A dim), col = l16 (B dim)
#pragma unroll
  for (int mi = 0; mi < MT; ++mi)
#pragma unroll
    for (int ni = 0; ni < 4; ++ni) {
      int col = bx * 128 + wn * 64 + ni * 16 + l16;
      float bv = bias[col];
      int row0 = by * (32 * MT) + wm * (MT * 16) + mi * 16 + quad * 4;
      if (EPI == 1) {
#pragma unroll
        for (int r = 0; r < 4; ++r)
          c_out[(size_t)(row0 + r) * N + col] = acc[mi][ni][r] + bv;
      } else {
        int which = col >> 10, rem = col & 1023;
        int h = rem >> 6, d = rem & 63;
        int b = row0 >> 11, sq0 = row0 & 2047;
        int bh = (b << 4) + h;
        if (which == 2) {
          // V fp16 transposed [bh][d][t]; 4 consecutive t -> one 8B store
          ushort4 pk;
          pk.x = f2h(acc[mi][ni][0] + bv);
          pk.y = f2h(acc[mi][ni][1] + bv);
          pk.z = f2h(acc[mi][ni][2] + bv);
          pk.w = f2h(acc[mi][ni][3] + bv);
          *reinterpret_cast<ushort4*>(&vt_out[(size_t)bh * 131072 + d * 2048 + sq0]) = pk;
        } else {
          size_t base = (size_t)(bh * 2048 + sq0) * 64 + d;
#pragma unroll
          for (int r = 0; r < 4; ++r) {
            float val = acc[mi][ni][r] + bv;
            if (which == 0) q_out[base + r * 64] = f2bf(val * QSCALE);
            else            k_out[base + r * 64] = f2bf(val);
          }
        }
      }
    }
}

// ---------------- flash attention (all-x32 MFMA, zero-barrier loop) ----------
// 64 Q rows/block, 4 waves t-split, 32 t/wave/iter (block iter = 128 t, 16
// iters). QK feeds permuted K-rows t = 8*(l16>>2)+(l16&3) (+4 for tile B) so
// the two S^T C-tiles give lane t = quad*8+j for q=l16 — exactly the
// mfma_f32_16x16x32_f16 A-frag: P is a register half8, PV runs at x32 rate.
// K and V frags loaded JIT at iter top (single-set: fits 3 waves/SIMD without
// spill — R7's ka double-buffer + unroll-2 spilled o_acc to scratch, 140 MB
// of scratch writes). No LDS / no barriers in the loop; 16 KB LDS only for
// the final cross-wave O/l reduction. Grid (bh, q): one bh's blocks share an
// XCD -> K/V stay L2-resident (FETCH 12 MB).
__global__ __launch_bounds__(256, 3) void attn(
    const u16* __restrict__ q_buf, const u16* __restrict__ k_buf,
    const u16* __restrict__ vt_buf, u16* __restrict__ o_buf) {
  __shared__ __align__(16) float red[4][4][256];  // 16 KB
  __shared__ float lred[4][16];

  const int tid = threadIdx.x;
  const int lane = tid & 63, w = tid >> 6;
  const int l16 = lane & 15, quad = lane >> 4;
  const int bh = blockIdx.x, q0 = blockIdx.y * 64;

  const u16* qg = q_buf + (size_t)bh * 131072 + q0 * 64;
  // permuted K row for QK tile A: t = w*32 + 8*(l16>>2) + (l16&3)
  const u16* kp = k_buf + (size_t)bh * 131072 +
                  (w * 32 + ((l16 >> 2) << 3) + (l16 & 3)) * 64 + quad * 8;
  // V [d][t]: lane d=l16 (tile nd adds 16), t = w*32 + quad*8
  const u16* vp = vt_buf + (size_t)bh * 131072 + l16 * 2048 + w * 32 + quad * 8;

  // Q B-frags (loop-invariant): n=q=l16, k = kk*32 + quad*8 + j
  short8 qb[4][2];
#pragma unroll
  for (int qi = 0; qi < 4; ++qi)
#pragma unroll
    for (int kk = 0; kk < 2; ++kk)
      qb[qi][kk] = *reinterpret_cast<const short8*>(
          qg + (qi * 16 + l16) * 64 + kk * 32 + quad * 8);

  const f32x4 fzero = {0.0f, 0.0f, 0.0f, 0.0f};
  f32x4 o_acc[4][4];
  float l_acc[4] = {0.f, 0.f, 0.f, 0.f};
#pragma unroll
  for (int qi = 0; qi < 4; ++qi)
#pragma unroll
    for (int nd = 0; nd < 4; ++nd) o_acc[qi][nd] = fzero;

#pragma unroll 1
  for (int i = 0; i < 16; ++i) {
    // K frags for this iter (single set, JIT — issued first, waited first)
    short8 ka0 = *reinterpret_cast<const short8*>(kp);
    short8 ka1 = *reinterpret_cast<const short8*>(kp + 32);
    short8 ka2 = *reinterpret_cast<const short8*>(kp + 256);   // +4 rows
    short8 ka3 = *reinterpret_cast<const short8*>(kp + 288);
    // V frags (issued after K; consumed after QK+exp2 -> latency hidden)
    half8 vf[4];
#pragma unroll
    for (int nd = 0; nd < 4; ++nd)
      vf[nd] = *reinterpret_cast<const half8*>(vp + nd * 16 * 2048);

#pragma unroll
    for (int qi = 0; qi < 4; ++qi) {
      // S^T tiles A/B: m = permuted t, n = q
      f32x4 sA = __builtin_amdgcn_mfma_f32_16x16x32_bf16(ka0, qb[qi][0], fzero, 0, 0, 0);
      sA = __builtin_amdgcn_mfma_f32_16x16x32_bf16(ka1, qb[qi][1], sA, 0, 0, 0);
      f32x4 sB = __builtin_amdgcn_mfma_f32_16x16x32_bf16(ka2, qb[qi][0], fzero, 0, 0, 0);
      sB = __builtin_amdgcn_mfma_f32_16x16x32_bf16(ka3, qb[qi][1], sB, 0, 0, 0);
      // P = exp2(S^T): lane q=l16 holds t = quad*8 + {0..3 from A, 4..7 from B}
      float p0 = __builtin_amdgcn_exp2f(sA[0]);
      float p1 = __builtin_amdgcn_exp2f(sA[1]);
      float p2 = __builtin_amdgcn_exp2f(sA[2]);
      float p3 = __builtin_amdgcn_exp2f(sA[3]);
      float p4 = __builtin_amdgcn_exp2f(sB[0]);
      float p5 = __builtin_amdgcn_exp2f(sB[1]);
      float p6 = __builtin_amdgcn_exp2f(sB[2]);
      float p7 = __builtin_amdgcn_exp2f(sB[3]);
      l_acc[qi] += ((p0 + p1) + (p2 + p3)) + ((p4 + p5) + (p6 + p7));
      half8 pa;
      pa[0] = (_Float16)p0; pa[1] = (_Float16)p1;
      pa[2] = (_Float16)p2; pa[3] = (_Float16)p3;
      pa[4] = (_Float16)p4; pa[5] = (_Float16)p5;
      pa[6] = (_Float16)p6; pa[7] = (_Float16)p7;
      // O += P.V at x32 rate
#pragma unroll
      for (int nd = 0; nd < 4; ++nd)
        o_acc[qi][nd] = __builtin_amdgcn_mfma_f32_16x16x32_f16(pa, vf[nd], o_acc[qi][nd], 0, 0, 0);
    }
    kp += 128 * 64;
    vp += 128;
  }

  // l: reduce across quads -> every lane holds this wave's l for q=l16
#pragma unroll
  for (int qi = 0; qi < 4; ++qi) {
    l_acc[qi] += __shfl_xor(l_acc[qi], 16, 64);
    l_acc[qi] += __shfl_xor(l_acc[qi], 32, 64);
  }

  // cross-wave O/l reduction per qi-phase through LDS
  const int b = bh >> 4, h = bh & 15;
#pragma unroll
  for (int qi = 0; qi < 4; ++qi) {
#pragma unroll
    for (int nd = 0; nd < 4; ++nd)
      *reinterpret_cast<f32x4*>(&red[w][nd][lane * 4]) = o_acc[qi][nd];
    if (lane < 16) lred[w][lane] = l_acc[qi];
    __syncthreads();
    // wave w reduces & writes d-columns [w*16, w*16+16)
    f32x4 os = fzero, lv = fzero;
#pragma unroll
    for (int wp = 0; wp < 4; ++wp) {
      os += *reinterpret_cast<const f32x4*>(&red[wp][w][lane * 4]);
      lv += *reinterpret_cast<const f32x4*>(&lred[wp][quad * 4]);
    }
#pragma unroll
    for (int r = 0; r < 4; ++r) {
      int sq = q0 + qi * 16 + quad * 4 + r;
      o_buf[(size_t)(b * 2048 + sq) * 1024 + h * 64 + w * 16 + l16] =
          f2bf(os[r] / lv[r]);
    }
    __syncthreads();
  }
}

extern "C" void kernel_launch(void* const* d_in, const int* in_sizes, int n_in,
                              void* d_out, int out_size, void* d_ws, size_t ws_size,
                              hipStream_t stream) {
  (void)in_sizes; (void)n_in; (void)out_size; (void)ws_size;
  const float* x     = (const float*)d_in[0];
  const float* W_qkv = (const float*)d_in[1];
  const float* b_qkv = (const float*)d_in[2];
  const float* W_out = (const float*)d_in[3];
  const float* b_out = (const float*)d_in[4];
  float* out = (float*)d_out;

  // workspace layout (48 MB total)
  char* ws = (char*)d_ws;
  u16* x_bf   = (u16*)(ws);              //  8 MB  [4096][1024] bf16
  u16* wqkv_t = (u16*)(ws + 8388608);    //  6 MB  [3072][1024] bf16
  u16* wout_t = (u16*)(ws + 14680064);   //  2 MB  [1024][1024] bf16
  u16* q_buf  = (u16*)(ws + 16777216);   //  8 MB  [32][2048][64] bf16
  u16* k_buf  = (u16*)(ws + 25165824);   //  8 MB  [32][2048][64] bf16
  u16* vt_buf = (u16*)(ws + 33554432);   //  8 MB  [32][64][2048] fp16 V^T
  u16* o_bf   = (u16*)(ws + 41943040);   //  8 MB  [4096][1024] bf16

  cvt_x<<<4096, 256, 0, stream>>>(x, x_bf);
  transpose_w<<<dim3(96, 32), 256, 0, stream>>>(W_qkv, wqkv_t, 1024, 3072);
  transpose_w<<<dim3(32, 32), 256, 0, stream>>>(W_out, wout_t, 1024, 1024);
  gemm_bt<0, 4><<<dim3(24, 32), 256, 0, stream>>>(x_bf, wqkv_t, b_qkv, nullptr,
                                                  q_buf, k_buf, vt_buf, 4096, 3072, 1024);
  attn<<<dim3(32, 32), 256, 0, stream>>>(q_buf, k_buf, vt_buf, o_bf);
  gemm_bt<1, 2><<<dim3(8, 64), 256, 0, stream>>>(o_bf, wout_t, b_out, out,
                                                 nullptr, nullptr, nullptr, 4096, 1024, 1024);
}